// Round 2
// baseline (305.693 us; speedup 1.0000x reference)
//
#include <hip/hip_runtime.h>
#include <math.h>

#define TPB 256

// ---------------- layer geometry ----------------
constexpr int DIMS_[5]  = {480, 240, 120, 60, 30};
constexpr int CHS_ [5]  = {64, 128, 256, 512, 512};
constexpr int CHB_ [5]  = {0, 64, 192, 448, 960};
constexpr int TOTCH     = 1472;
constexpr int PROCB_[5] = {0, 230400, 288000, 302400, 306000};
constexpr int PROCTOT   = 306900;

// ---------------- ws layout (4-byte words) ----------------
constexpr int O_CHMIN = 0;                  // f32 [1472]
constexpr int O_CHMAX = 1472;               // f32 [1472]
constexpr int O_HIST  = 2944;               // u32 [1472*6]: slots 0..4 = raw count(v>=th[k])
constexpr int O_GCNT  = 11776;              // u32 [1472*6]: slots 0..4 = raw count(v>=tg[k])
constexpr int O_CLUT  = 20608;              // f32 [1472*16]: gthr[0..4], pad, lut[8..13]
constexpr int O_BSUM  = O_CLUT + 16 * 1472; // 44160: f32 [5]
constexpr int O_PMIN  = O_BSUM + 5;         // u32 [5]
constexpr int O_PMAX  = O_PMIN + 5;         // u32 [5]
constexpr int O_S3MIN = O_PMAX + 5;         // u32 [5]
constexpr int O_S3MAX = O_S3MIN + 5;        // u32 [5]
constexpr int O_S3SUM = O_S3MAX + 5;        // f32 [5]
constexpr int O_PROC  = 44192;              // f32 [306900] (zero-init; chunked layers atomicAdd)
constexpr int O_RESZ  = O_PROC + PROCTOT;   // f32 [5*57600]
constexpr int N_INIT  = O_PROC + PROCTOT;   // init range

struct P {
  const float* in[5];
  float* ws;
};

// ---------------- threshold helpers (same formulas everywhere) ----------------
// hist compare k: v >= mn + rng*(k+1)/6
// gidx compare k: v >= mn + rng*(k+2)/1536
__device__ __forceinline__ void mk_hthr(float mn, float rng, float* th) {
  if (rng == 0.0f) { th[0]=th[1]=th[2]=th[3]=th[4]=INFINITY; return; }
  th[0] = mn + rng * (1.0f / 6.0f); th[1] = mn + rng * (2.0f / 6.0f);
  th[2] = mn + rng * (3.0f / 6.0f); th[3] = mn + rng * (4.0f / 6.0f);
  th[4] = mn + rng * (5.0f / 6.0f);
}
__device__ __forceinline__ void mk_gthr(float mn, float rng, float* tg) {
  if (rng == 0.0f) { tg[0]=tg[1]=tg[2]=tg[3]=tg[4]=INFINITY; return; }
  tg[0] = mn + rng * (2.0f / 1536.0f); tg[1] = mn + rng * (3.0f / 1536.0f);
  tg[2] = mn + rng * (4.0f / 1536.0f); tg[3] = mn + rng * (5.0f / 1536.0f);
  tg[4] = mn + rng * (6.0f / 1536.0f);
}

// ---------------- init ----------------
__global__ void k_init(float* ws) {
  int i = blockIdx.x * TPB + threadIdx.x;
  if (i >= N_INIT) return;
  unsigned v = 0u;
  if (i < O_CHMAX) v = 0x7F800000u;                       // chmin = +inf
  else if (i >= O_PMIN  && i < O_PMAX)  v = 0x7F800000u;  // pmin
  else if (i >= O_S3MIN && i < O_S3MAX) v = 0x7F800000u;  // s3min
  ((unsigned*)ws)[i] = v;
}

// ---------------- pass A: per-channel min/max of border-zeroed map ----------------
// Full 4096-vec chunks use a software-pipelined (register double-buffered)
// loop: prefetch next 4 float4 while computing current 4, so the compiler
// emits counted vmcnt instead of a drain -> L3 latency hidden under compute.
template <int D, int DQ>
__device__ __forceinline__ void zb4(int f4i, float4& v) {
  int y = f4i / DQ, xq = f4i - y * DQ;
  if (y == 0 || y == D - 1) { v.x = v.y = v.z = v.w = 0.0f; }
  else {
    if (xq == 0)      v.x = 0.0f;
    if (xq == DQ - 1) v.w = 0.0f;
  }
}

template <int L>
__device__ void bodyA(int local, const float* __restrict__ in, float* ws) {
  constexpr int D = DIMS_[L], HW = D * D, HW4 = HW / 4;
  constexpr int BPC = (HW4 + 4095) / 4096;
  constexpr int DQ = D / 4;
  int ch = local / BPC, chunk = local % BPC;
  int nvec = HW4 - chunk * 4096; if (nvec > 4096) nvec = 4096;
  const float4* pv = (const float4*)(in + (size_t)ch * HW) + (size_t)chunk * 4096;
  int t = threadIdx.x;
  float mn = INFINITY, mx = 0.0f;
  auto MM4 = [&](float4 v) {
    mn = fminf(fminf(mn, fminf(v.x, v.y)), fminf(v.z, v.w));
    mx = fmaxf(fmaxf(mx, fmaxf(v.x, v.y)), fmaxf(v.z, v.w));
  };
  if constexpr (D % 4 == 0) {
    if (nvec == 4096) {
      int base = chunk * 4096;
      float4 a0 = pv[t], a1 = pv[t + TPB], a2 = pv[t + 2 * TPB], a3 = pv[t + 3 * TPB];
      #pragma unroll
      for (int g = 0; g < 4; g++) {
        float4 b0 = a0, b1 = a1, b2 = a2, b3 = a3;
        if (g < 3) {
          int o = (g + 1) * 4 * TPB + t;
          b0 = pv[o]; b1 = pv[o + TPB]; b2 = pv[o + 2 * TPB]; b3 = pv[o + 3 * TPB];
        }
        int i0 = base + g * 4 * TPB + t;
        zb4<D, DQ>(i0,           a0); MM4(a0);
        zb4<D, DQ>(i0 + TPB,     a1); MM4(a1);
        zb4<D, DQ>(i0 + 2 * TPB, a2); MM4(a2);
        zb4<D, DQ>(i0 + 3 * TPB, a3); MM4(a3);
        a0 = b0; a1 = b1; a2 = b2; a3 = b3;
      }
    } else {
      #pragma unroll 4
      for (int i = 0; i < 16; i++) {
        int vi = i * TPB + t;
        if (vi < nvec) {
          float4 v = pv[vi];
          zb4<D, DQ>(chunk * 4096 + vi, v);
          MM4(v);
        }
      }
    }
  } else {                              // D==30: f4 may straddle rows
    #pragma unroll 4
    for (int i = 0; i < 16; i++) {
      int vi = i * TPB + t;
      if (vi < nvec) {
        float4 v = pv[vi];
        float vv[4] = {v.x, v.y, v.z, v.w};
        int e0 = (chunk * 4096 + vi) * 4;
        #pragma unroll
        for (int j = 0; j < 4; j++) {
          int e = e0 + j, y = e / D, x = e - y * D;
          bool inr = ((unsigned)(x - 1) < (unsigned)(D - 2)) && ((unsigned)(y - 1) < (unsigned)(D - 2));
          if (!inr) vv[j] = 0.0f;
        }
        v.x = vv[0]; v.y = vv[1]; v.z = vv[2]; v.w = vv[3];
        MM4(v);
      }
    }
  }
  for (int o = 32; o; o >>= 1) { mn = fminf(mn, __shfl_down(mn, o)); mx = fmaxf(mx, __shfl_down(mx, o)); }
  __shared__ float smn[4], smx[4];
  int w = t >> 6;
  if ((t & 63) == 0) { smn[w] = mn; smx[w] = mx; }
  __syncthreads();
  if (t == 0) {
    mn = fminf(fminf(smn[0], smn[1]), fminf(smn[2], smn[3]));
    mx = fmaxf(fmaxf(smx[0], smx[1]), fmaxf(smx[2], smx[3]));
    int g = CHB_[L] + ch;
    atomicMin((unsigned*)ws + O_CHMIN + g, __float_as_uint(mn));  // values >= 0
    atomicMax((unsigned*)ws + O_CHMAX + g, __float_as_uint(mx));
  }
}
__global__ void kA(P p) {
  int b = blockIdx.x;
  if      (b <  960) bodyA<0>(b,        p.in[0], p.ws);
  else if (b < 1472) bodyA<1>(b -  960, p.in[1], p.ws);
  else if (b < 1728) bodyA<2>(b - 1472, p.in[2], p.ws);
  else if (b < 2240) bodyA<3>(b - 1728, p.in[3], p.ws);
  else               bodyA<4>(b - 2240, p.in[4], p.ws);
}

// ---- pass B: RAW monotone compare counts, no border logic in hot loop ----
// H/G slots 0..4 hold count(v_raw >= th[k]) summed over the whole channel.
// Border blocks (appended to the grid) SUBTRACT the raw border contributions;
// kS adds the analytic zero-border term (4D-4)*(0>=th[k]) and converts the
// monotone counts to bin counts. Semantics bitwise-identical to counting the
// border-zeroed map (same mk_hthr/mk_gthr compares everywhere).
template <int L>
__device__ void bodyB(int local, const float* __restrict__ in, float* ws) {
  constexpr int D = DIMS_[L], HW = D * D, HW4 = HW / 4;
  constexpr int BPC = (HW4 + 4095) / 4096;
  int ch = local / BPC, chunk = local % BPC;
  int g = CHB_[L] + ch;
  float mn = ws[O_CHMIN + g], mx = ws[O_CHMAX + g], rng = mx - mn;
  float th[5], tg[5];
  mk_hthr(mn, rng, th);
  mk_gthr(mn, rng, tg);
  int nvec = HW4 - chunk * 4096; if (nvec > 4096) nvec = 4096;
  const float4* pv = (const float4*)(in + (size_t)ch * HW) + (size_t)chunk * 4096;
  int t = threadIdx.x;
  unsigned c[10] = {0u,0u,0u,0u,0u,0u,0u,0u,0u,0u};  // c[0..4]=H, c[5..9]=G
  auto CNT = [&](float x) {
    #pragma unroll
    for (int k = 0; k < 5; k++) { c[k] += (x >= th[k]); c[5 + k] += (x >= tg[k]); }
  };
  auto CNT4 = [&](float4 v) { CNT(v.x); CNT(v.y); CNT(v.z); CNT(v.w); };
  if (nvec == 4096) {
    // software-pipelined: prefetch next 4 float4 while counting current 4
    float4 a0 = pv[t], a1 = pv[t + TPB], a2 = pv[t + 2 * TPB], a3 = pv[t + 3 * TPB];
    #pragma unroll
    for (int gq = 0; gq < 4; gq++) {
      float4 b0 = a0, b1 = a1, b2 = a2, b3 = a3;
      if (gq < 3) {
        int o = (gq + 1) * 4 * TPB + t;
        b0 = pv[o]; b1 = pv[o + TPB]; b2 = pv[o + 2 * TPB]; b3 = pv[o + 3 * TPB];
      }
      CNT4(a0); CNT4(a1); CNT4(a2); CNT4(a3);
      a0 = b0; a1 = b1; a2 = b2; a3 = b3;
    }
  } else {
    #pragma unroll 4
    for (int i = 0; i < 16; i++) {
      int vi = i * TPB + t;
      if (vi < nvec) CNT4(pv[vi]);
    }
  }
  #pragma unroll
  for (int k = 0; k < 10; k++)
    for (int o = 32; o; o >>= 1) c[k] += __shfl_down(c[k], o);
  if ((t & 63) == 0) {
    unsigned* H = (unsigned*)ws + O_HIST + g * 6;
    unsigned* G = (unsigned*)ws + O_GCNT + g * 6;
    #pragma unroll
    for (int k = 0; k < 5; k++) { atomicAdd(H + k, c[k]); atomicAdd(G + k, c[5 + k]); }
  }
}

// border-fix blocks: one block per channel, subtract raw border compare counts
__device__ void bodyBborder(int ch, P p) {
  float* ws = p.ws;
  int l = (ch < 64) ? 0 : (ch < 192) ? 1 : (ch < 448) ? 2 : (ch < 960) ? 3 : 4;
  int D = DIMS_[l];
  const float* src = p.in[l] + (size_t)(ch - CHB_[l]) * (D * D);
  float mn = ws[O_CHMIN + ch], mx = ws[O_CHMAX + ch], rng = mx - mn;
  float th[5], tg[5];
  mk_hthr(mn, rng, th);
  mk_gthr(mn, rng, tg);
  unsigned c[10] = {0u,0u,0u,0u,0u,0u,0u,0u,0u,0u};
  int nb = 4 * D - 4;
  for (int e = threadIdx.x; e < nb; e += TPB) {
    int x, y;
    if (e < D)          { y = 0; x = e; }
    else if (e < 2 * D) { y = D - 1; x = e - D; }
    else {
      int e2 = e - 2 * D;
      y = 1 + (e2 >> 1);
      x = (e2 & 1) ? (D - 1) : 0;
    }
    float v = src[y * D + x];
    #pragma unroll
    for (int k = 0; k < 5; k++) { c[k] += (v >= th[k]); c[5 + k] += (v >= tg[k]); }
  }
  #pragma unroll
  for (int k = 0; k < 10; k++)
    for (int o = 32; o; o >>= 1) c[k] += __shfl_down(c[k], o);
  if ((threadIdx.x & 63) == 0) {
    unsigned* H = (unsigned*)ws + O_HIST + ch * 6;
    unsigned* G = (unsigned*)ws + O_GCNT + ch * 6;
    #pragma unroll
    for (int k = 0; k < 5; k++) { atomicSub(H + k, c[k]); atomicSub(G + k, c[5 + k]); }
  }
}

__global__ void kB(P p) {
  int b = blockIdx.x;
  if (b >= 2752) { bodyBborder(b - 2752, p); return; }
  if      (b <  960) bodyB<0>(b,        p.in[0], p.ws);
  else if (b < 1472) bodyB<1>(b -  960, p.in[1], p.ws);
  else if (b < 1728) bodyB<2>(b - 1472, p.in[2], p.ws);
  else if (b < 2240) bodyB<3>(b - 1728, p.in[3], p.ws);
  else               bodyB<4>(b - 2240, p.in[4], p.ws);
}

// ---------------- kernel S: per-channel LUT construction ----------------
__global__ void kS(P p) {
  int ch = blockIdx.x * TPB + threadIdx.x;
  if (ch >= TOTCH) return;
  float* ws = p.ws;
  int l = (ch < 64) ? 0 : (ch < 192) ? 1 : (ch < 448) ? 2 : (ch < 960) ? 3 : 4;
  int D = DIMS_[l];
  int HW = D * D;
  int c0 = ch - CHB_[l];
  // ---- reconstruct border-zeroed bin counts from raw monotone counts ----
  unsigned* H = (unsigned*)ws + O_HIST + ch * 6;
  unsigned* G = (unsigned*)ws + O_GCNT + ch * 6;
  unsigned cH[5], cG[5];
  #pragma unroll
  for (int k = 0; k < 5; k++) { cH[k] = H[k]; cG[k] = G[k]; }
  float mnc = ws[O_CHMIN + ch], mxc = ws[O_CHMAX + ch];
  float thh[5], tg[5];
  mk_hthr(mnc, mxc - mnc, thh);
  mk_gthr(mnc, mxc - mnc, tg);
  unsigned bcnt = (unsigned)(4 * D - 4);
  unsigned czH[5], czG[5];
  #pragma unroll
  for (int k = 0; k < 5; k++) {
    czH[k] = cH[k] + bcnt * (unsigned)(0.0f >= thh[k]);
    czG[k] = cG[k] + bcnt * (unsigned)(0.0f >= tg[k]);
  }
  unsigned hc[6], gc[6];
  hc[0] = (unsigned)HW - czH[0]; hc[5] = czH[4];
  gc[0] = (unsigned)HW - czG[0]; gc[5] = czG[4];
  #pragma unroll
  for (int k = 1; k < 5; k++) { hc[k] = czH[k - 1] - czH[k]; gc[k] = czG[k - 1] - czG[k]; }
  // ---- original LUT math ----
  float HWf = (float)HW;
  float nh[6];
  #pragma unroll
  for (int k = 0; k < 6; k++) nh[k] = -logf((float)hc[k] / HWf + 1e-4f);
  float dmn = INFINITY, dmx = -INFINITY;
  #pragma unroll
  for (int k = 0; k < 6; k++) if (gc[k]) { dmn = fminf(dmn, nh[k]); dmx = fmaxf(dmx, nh[k]); }
  float dr = dmx - dmn;
  float dstn[6];
  #pragma unroll
  for (int k = 0; k < 6; k++) dstn[k] = (dr == 0.0f) ? 0.0f : ((nh[k] - dmn) / dr);
  float maxv = (dr == 0.0f) ? 0.0f : 1.0f;
  double s1 = 0.0;
  #pragma unroll
  for (int k = 0; k < 6; k++) s1 += (double)gc[k] * (double)dstn[k];
  float mean1 = (float)(s1 / (double)HW);
  float w1 = maxv - mean1; w1 *= w1;
  float lut1[6];
  #pragma unroll
  for (int k = 0; k < 6; k++) lut1[k] = dstn[k] * w1;
  int gb = (0.0f >= tg[0]) + (0.0f >= tg[1]) + (0.0f >= tg[2]) + (0.0f >= tg[3]) + (0.0f >= tg[4]);
  float lmn, lmx;
  double s2 = 0.0;
  if (c0 == 0) {   // channel 0 keeps its border
    lmn = INFINITY; lmx = -INFINITY;
    #pragma unroll
    for (int k = 0; k < 6; k++) if (gc[k]) {
      lmn = fminf(lmn, lut1[k]); lmx = fmaxf(lmx, lut1[k]);
      s2 += (double)gc[k] * (double)lut1[k];
    }
  } else {
    lmn = 0.0f; lmx = 0.0f;   // border zeros present
    #pragma unroll
    for (int k = 0; k < 6; k++) {
      unsigned ic = gc[k] - ((k == gb) ? bcnt : 0u);
      if (ic) {
        lmn = fminf(lmn, lut1[k]); lmx = fmaxf(lmx, lut1[k]);
        s2 += (double)ic * (double)lut1[k];
      }
    }
  }
  float mean2 = (float)(s2 / (double)HW);
  float w2 = lmx - mean2; w2 *= w2;
  float r2 = lmx - lmn;
  float lout[6];
  #pragma unroll
  for (int k = 0; k < 6; k++) lout[k] = (r2 == 0.0f) ? 0.0f : (((lut1[k] - lmn) / r2) * w2);
  // aligned LUT record: gthr at [0..4], lut at [8..13] (b128-friendly for kC)
  float* T = ws + O_CLUT + (size_t)ch * 16;
  #pragma unroll
  for (int k = 0; k < 5; k++) T[k] = tg[k];
  #pragma unroll
  for (int k = 0; k < 6; k++) T[8 + k] = lout[k];
  float bc = (c0 == 0) ? lout[gb] : ((r2 == 0.0f) ? 0.0f : (((0.0f - lmn) / r2) * w2));
  atomicAdd(ws + O_BSUM + l, bc);
}

// ---- pass C: proc = sum_c LUT[gb_c(v)] ----
// (64-float4 tile) x (64-channel chunk); 4 waves split the 64 channels.
// Channel loop is software-pipelined: prefetch next 4 channel values while
// computing current 4 (LUT from LDS, aligned layout).
template <int L>
__device__ void bodyC(int local, const float* __restrict__ in, float* ws,
                      float* slut, float* sred) {
  constexpr int D = DIMS_[L], HW = D * D, HW4 = HW / 4, C = CHS_[L];
  constexpr int NT  = (HW4 + 63) / 64;   // tiles per layer
  constexpr int NCH = C / 64;            // channel chunks
  int tile = local % NT, chunk = local / NT;
  int cbase = CHB_[L] + chunk * 64;
  int t = threadIdx.x, lane = t & 63, w = t >> 6;
  const float* gl = ws + O_CLUT + (size_t)cbase * 16;
  for (int i = t; i < 1024; i += TPB) slut[i] = gl[i];
  __syncthreads();
  int p4 = tile * 64 + lane;
  bool valid = p4 < HW4;
  float a0 = 0.0f, a1 = 0.0f, a2 = 0.0f, a3 = 0.0f;
  if (valid) {
    const float4* bp = (const float4*)in + (size_t)(chunk * 64 + w * 16) * HW4 + p4;
    const float* su = slut + (w * 16) * 16;
    auto PROC = [&](float4 v, int c) {
      const float* cl = su + c * 16;
      float g0 = cl[0], g1 = cl[1], g2 = cl[2], g3 = cl[3], g4 = cl[4];
      float l0 = cl[8], l1 = cl[9], l2 = cl[10], l3 = cl[11], l4 = cl[12], l5 = cl[13];
      float s;
      s = (v.x >= g0) ? l1 : l0; s = (v.x >= g1) ? l2 : s; s = (v.x >= g2) ? l3 : s;
      s = (v.x >= g3) ? l4 : s;  s = (v.x >= g4) ? l5 : s; a0 += s;
      s = (v.y >= g0) ? l1 : l0; s = (v.y >= g1) ? l2 : s; s = (v.y >= g2) ? l3 : s;
      s = (v.y >= g3) ? l4 : s;  s = (v.y >= g4) ? l5 : s; a1 += s;
      s = (v.z >= g0) ? l1 : l0; s = (v.z >= g1) ? l2 : s; s = (v.z >= g2) ? l3 : s;
      s = (v.z >= g3) ? l4 : s;  s = (v.z >= g4) ? l5 : s; a2 += s;
      s = (v.w >= g0) ? l1 : l0; s = (v.w >= g1) ? l2 : s; s = (v.w >= g2) ? l3 : s;
      s = (v.w >= g3) ? l4 : s;  s = (v.w >= g4) ? l5 : s; a3 += s;
    };
    float4 va0 = bp[0], va1 = bp[(size_t)HW4], va2 = bp[(size_t)2 * HW4], va3 = bp[(size_t)3 * HW4];
    #pragma unroll
    for (int gq = 0; gq < 4; gq++) {
      float4 vb0 = va0, vb1 = va1, vb2 = va2, vb3 = va3;
      if (gq < 3) {
        const float4* np = bp + (size_t)(gq + 1) * 4 * HW4;
        vb0 = np[0]; vb1 = np[(size_t)HW4]; vb2 = np[(size_t)2 * HW4]; vb3 = np[(size_t)3 * HW4];
      }
      PROC(va0, gq * 4 + 0); PROC(va1, gq * 4 + 1);
      PROC(va2, gq * 4 + 2); PROC(va3, gq * 4 + 3);
      va0 = vb0; va1 = vb1; va2 = vb2; va3 = vb3;
    }
  }
  sred[0 * 256 + w * 64 + lane] = a0;
  sred[1 * 256 + w * 64 + lane] = a1;
  sred[2 * 256 + w * 64 + lane] = a2;
  sred[3 * 256 + w * 64 + lane] = a3;
  __syncthreads();
  if (w == 0 && valid) {
    float o[4];
    #pragma unroll
    for (int j = 0; j < 4; j++)
      o[j] = sred[j * 256 + lane] + sred[j * 256 + 64 + lane] +
             sred[j * 256 + 128 + lane] + sred[j * 256 + 192 + lane];
    float bs = ws[O_BSUM + L];
    float* procL = ws + O_PROC + PROCB_[L];
    int px0 = p4 * 4;
    if constexpr (NCH == 1) {
      #pragma unroll
      for (int j = 0; j < 4; j++) {
        int px = px0 + j, y = px / D, x = px - y * D;
        bool inr = ((unsigned)(x - 1) < (unsigned)(D - 2)) && ((unsigned)(y - 1) < (unsigned)(D - 2));
        if (!inr) o[j] = bs;
      }
      ((float4*)procL)[p4] = make_float4(o[0], o[1], o[2], o[3]);
    } else {
      #pragma unroll
      for (int j = 0; j < 4; j++) {
        int px = px0 + j, y = px / D, x = px - y * D;
        bool inr = ((unsigned)(x - 1) < (unsigned)(D - 2)) && ((unsigned)(y - 1) < (unsigned)(D - 2));
        if (inr) atomicAdd(procL + px, o[j]);
        else if (chunk == 0) procL[px] = bs;   // sole writer of border pixels
      }
    }
  }
}
__global__ __launch_bounds__(TPB) void kC(P p) {
  __shared__ float slut[1024];
  __shared__ float sred[1024];
  int b = blockIdx.x;
  if      (b <  900) bodyC<0>(b,        p.in[0], p.ws, slut, sred);
  else if (b < 1350) bodyC<1>(b -  900, p.in[1], p.ws, slut, sred);
  else if (b < 1578) bodyC<2>(b - 1350, p.in[2], p.ws, slut, sred);
  else if (b < 1698) bodyC<3>(b - 1578, p.in[3], p.ws, slut, sred);
  else               bodyC<4>(b - 1698, p.in[4], p.ws, slut, sred);
}

// ---------------- pass D: per-layer proc min/max ----------------
template <int L>
__device__ void bodyD(int chunk, float* ws) {
  constexpr int HW = DIMS_[L] * DIMS_[L];
  const float* pr = ws + O_PROC + PROCB_[L];
  int t = threadIdx.x;
  float mn = INFINITY, mx = 0.0f;   // proc >= 0
  #pragma unroll
  for (int i = 0; i < 16; i++) {
    int idx = chunk * 4096 + i * TPB + t;
    if (idx < HW) { float v = pr[idx]; mn = fminf(mn, v); mx = fmaxf(mx, v); }
  }
  for (int o = 32; o; o >>= 1) { mn = fminf(mn, __shfl_down(mn, o)); mx = fmaxf(mx, __shfl_down(mx, o)); }
  __shared__ float smn[4], smx[4];
  int w = t >> 6;
  if ((t & 63) == 0) { smn[w] = mn; smx[w] = mx; }
  __syncthreads();
  if (t == 0) {
    mn = fminf(fminf(smn[0], smn[1]), fminf(smn[2], smn[3]));
    mx = fmaxf(fmaxf(smx[0], smx[1]), fmaxf(smx[2], smx[3]));
    atomicMin((unsigned*)ws + O_PMIN + L, __float_as_uint(mn));
    atomicMax((unsigned*)ws + O_PMAX + L, __float_as_uint(mx));
  }
}
__global__ void kD(P p) {
  int b = blockIdx.x;
  if      (b < 57) bodyD<0>(b,      p.ws);
  else if (b < 72) bodyD<1>(b - 57, p.ws);
  else if (b < 76) bodyD<2>(b - 72, p.ws);
  else if (b < 77) bodyD<3>(b - 76, p.ws);
  else             bodyD<4>(b - 77, p.ws);
}

// ---- pass F: normalize(proc,0,1) + threshold + jax bilinear resize, fused layer stats ----
template <int L>
__device__ float bodyF(int px, float* ws) {
  constexpr int D = DIMS_[L];
  constexpr float INV = (float)D / 240.0f;
  constexpr float KS = (INV > 1.0f) ? INV : 1.0f;
  int oy = px / 240, ox = px - oy * 240;
  float mnv = __uint_as_float(((unsigned*)ws)[O_PMIN + L]);
  float mxv = __uint_as_float(((unsigned*)ws)[O_PMAX + L]);
  float pr = mxv - mnv;
  const float* procL = ws + O_PROC + PROCB_[L];
  float sfy = ((float)oy + 0.5f) * INV - 0.5f;
  float sfx = ((float)ox + 0.5f) * INV - 0.5f;
  int y0 = (int)ceilf(sfy - KS);  if (y0 < 0) y0 = 0;
  int y1 = (int)floorf(sfy + KS); if (y1 > D - 1) y1 = D - 1;
  int x0 = (int)ceilf(sfx - KS);  if (x0 < 0) x0 = 0;
  int x1 = (int)floorf(sfx + KS); if (x1 > D - 1) x1 = D - 1;
  float wsx = 0.0f;
  for (int jx = x0; jx <= x1; jx++) wsx += fmaxf(1.0f - fabsf(sfx - (float)jx) / KS, 0.0f);
  float acc = 0.0f, wsy = 0.0f;
  for (int jy = y0; jy <= y1; jy++) {
    float wy = fmaxf(1.0f - fabsf(sfy - (float)jy) / KS, 0.0f);
    wsy += wy;
    if (wy > 0.0f) {
      const float* row = procL + jy * D;
      float rs = 0.0f;
      for (int jx = x0; jx <= x1; jx++) {
        float wx = fmaxf(1.0f - fabsf(sfx - (float)jx) / KS, 0.0f);
        if (wx > 0.0f) {
          float v = row[jx];
          float tv = (pr == 0.0f) ? 0.0f : ((v - mnv) / pr);
          tv = (tv < 0.2f) ? 0.0f : tv;
          rs += wx * tv;
        }
      }
      acc += wy * rs;
    }
  }
  return acc / (wsy * wsx);
}
__global__ void kF(P p) {
  float* ws = p.ws;
  int b = blockIdx.x, l = b / 225;
  int px = (b - l * 225) * TPB + threadIdx.x;
  float res;
  switch (l) {
    case 0: res = bodyF<0>(px, ws); break;
    case 1: res = bodyF<1>(px, ws); break;
    case 2: res = bodyF<2>(px, ws); break;
    case 3: res = bodyF<3>(px, ws); break;
    default: res = bodyF<4>(px, ws); break;
  }
  ws[O_RESZ + l * 57600 + px] = res;
  float mn = res, mx = res, s = res;
  for (int o = 32; o; o >>= 1) {
    mn = fminf(mn, __shfl_down(mn, o));
    mx = fmaxf(mx, __shfl_down(mx, o));
    s += __shfl_down(s, o);
  }
  __shared__ float smn[4], smx[4], ssm[4];
  int t = threadIdx.x, w = t >> 6;
  if ((t & 63) == 0) { smn[w] = mn; smx[w] = mx; ssm[w] = s; }
  __syncthreads();
  if (t == 0) {
    mn = fminf(fminf(smn[0], smn[1]), fminf(smn[2], smn[3]));
    mx = fmaxf(fmaxf(smx[0], smx[1]), fmaxf(smx[2], smx[3]));
    s = ssm[0] + ssm[1] + ssm[2] + ssm[3];
    atomicMin((unsigned*)ws + O_S3MIN + l, __float_as_uint(mn));
    atomicMax((unsigned*)ws + O_S3MAX + l, __float_as_uint(mx));
    atomicAdd(ws + O_S3SUM + l, s);
  }
}

// ---------------- G2: final ponder + normalize(.,0,256), groups + sum ----------------
__global__ void kG2(P p, float* __restrict__ out) {
  float* ws = p.ws;
  int px = blockIdx.x * TPB + threadIdx.x;   // 225*256 == 57600
  float sum = 0.0f;
  #pragma unroll
  for (int l = 0; l < 5; l++) {
    float v = ws[O_RESZ + l * 57600 + px];
    float mn3 = __uint_as_float(((unsigned*)ws)[O_S3MIN + l]);
    float mx3 = __uint_as_float(((unsigned*)ws)[O_S3MAX + l]);
    float mean3 = ws[O_S3SUM + l] / 57600.0f;
    float r3 = mx3 - mn3;
    float ov;
    if (r3 == 0.0f) ov = 0.0f;
    else {
      float w3 = mx3 - mean3; w3 *= w3;
      if (w3 == 0.0f) ov = 0.0f;
      else ov = ((v - mn3) / r3) * w3 / w3 * 256.0f;
    }
    out[57600 + px * 5 + l] = ov;
    sum += ov;
  }
  out[px] = sum;
}

extern "C" void kernel_launch(void* const* d_in, const int* in_sizes, int n_in,
                              void* d_out, int out_size, void* d_ws, size_t ws_size,
                              hipStream_t stream) {
  (void)in_sizes; (void)n_in; (void)out_size; (void)ws_size;
  P p;
  for (int i = 0; i < 5; i++) p.in[i] = (const float*)d_in[i];
  p.ws = (float*)d_ws;
  float* out = (float*)d_out;

  k_init<<<(N_INIT + TPB - 1) / TPB, TPB, 0, stream>>>(p.ws);
  kA  <<<2752, TPB, 0, stream>>>(p);
  kB  <<<2752 + TOTCH, TPB, 0, stream>>>(p);   // +1472 border-fix blocks
  kS  <<<6,    TPB, 0, stream>>>(p);
  kC  <<<1730, TPB, 0, stream>>>(p);
  kD  <<<78,   TPB, 0, stream>>>(p);
  kF  <<<1125, TPB, 0, stream>>>(p);
  kG2 <<<225,  TPB, 0, stream>>>(p, out);
}